// Round 4
// baseline (258.904 us; speedup 1.0000x reference)
//
#include <hip/hip_runtime.h>
#include <hip/hip_bf16.h>

typedef unsigned int u32;

#define NPAIR 32
#define NCLS  92
#define NCTX  8
#define MAXL  40
#define DIM   768
#define LSUF  31

#define MAT_ELEMS 90439680u      // 32*92*40*768  (f32 elements)
#define MAT_VECS  11304960u      // MAT_ELEMS/8   (8-float chunks)
#define TOTAL_MAT 22609920u      // 2*MAT_VECS
#define MASK_VECS 14720u         // 117760/8
#define TOTAL_WORK 22624640u     // TOTAL_MAT + MASK_VECS
#define MASK_BASE 180879360u     // 2*MAT_ELEMS (f32 element offset)

// ---------------- kernel 1: gather + MLP + 8-way attention ----------------
// one block per pair, 256 threads; all float inputs f32
__global__ __launch_bounds__(256) void k_mlp_att(
    const int* __restrict__ so_ids,     // (32,2) int32 (int64 layout auto-detected)
    const float* __restrict__ enti,     // (36,256) f32
    const float* __restrict__ meta,     // (8,768) f32
    const float* __restrict__ W1,       // (512,256) f32
    const float* __restrict__ b1,       // (256) f32
    const float* __restrict__ W2,       // (256,1536) f32
    float* __restrict__ att)            // out: (2,32,768) f32 in d_ws
{
    const int p = blockIdx.x;
    const int t = threadIdx.x;
    __shared__ float so_vec[512];
    __shared__ float h[256];
    __shared__ float so_e[1536];
    __shared__ float red[8][256];
    __shared__ float probs[8];
    __shared__ int ids[2];

    if (t == 0) {
        // int64-vs-int32 layout detection: ids in [0,36), so an int64 buffer has
        // all-zero odd int32 words in the first 64 words. (No-op for int32.)
        bool is64 = true;
        for (int i = 1; i < 64; i += 2) is64 = is64 && (so_ids[i] == 0);
        if (is64) { ids[0] = so_ids[4 * p];     ids[1] = so_ids[4 * p + 2]; }
        else      { ids[0] = so_ids[2 * p];     ids[1] = so_ids[2 * p + 1]; }
    }
    __syncthreads();
    const int s_id = ids[0];
    const int o_id = ids[1];
    so_vec[t]       = enti[s_id * 256 + t];
    so_vec[256 + t] = enti[o_id * 256 + t];
    __syncthreads();

    // h = relu(so @ W1 + b1); thread t owns column t (coalesced W1 reads)
    float acc = b1[t];
    #pragma unroll 8
    for (int k = 0; k < 512; ++k)
        acc = fmaf(so_vec[k], W1[k * 256 + t], acc);
    h[t] = fmaxf(acc, 0.0f);
    __syncthreads();

    // so_e = h @ W2; thread t owns columns t, t+256, ..., t+1280
    float a6[6] = {0.f, 0.f, 0.f, 0.f, 0.f, 0.f};
    #pragma unroll 4
    for (int k = 0; k < 256; ++k) {
        const float hk = h[k];
        #pragma unroll
        for (int r = 0; r < 6; ++r)
            a6[r] = fmaf(hk, W2[k * 1536 + r * 256 + t], a6[r]);
    }
    #pragma unroll
    for (int r = 0; r < 6; ++r) so_e[r * 256 + t] = a6[r];
    __syncthreads();

    const float scale = 0.036084391824351615f;  // 1/sqrt(768)
    for (int which = 0; which < 2; ++which) {
        const float* q = &so_e[which * DIM];
        #pragma unroll
        for (int c = 0; c < 8; ++c) {
            float pp = 0.f;
            #pragma unroll
            for (int i = 0; i < 3; ++i) {
                const int d = t + 256 * i;
                pp = fmaf(q[d], meta[c * DIM + d], pp);
            }
            red[c][t] = pp;
        }
        __syncthreads();
        for (int s = 128; s > 0; s >>= 1) {
            if (t < s) {
                #pragma unroll
                for (int c = 0; c < 8; ++c)
                    red[c][t] += red[c][t + s];
            }
            __syncthreads();
        }
        if (t == 0) {
            float sc[8], m = -1e30f;
            #pragma unroll
            for (int c = 0; c < 8; ++c) { sc[c] = red[c][0] * scale; m = fmaxf(m, sc[c]); }
            float sum = 0.f;
            #pragma unroll
            for (int c = 0; c < 8; ++c) { sc[c] = expf(sc[c] - m); sum += sc[c]; }
            const float inv = 1.f / sum;
            #pragma unroll
            for (int c = 0; c < 8; ++c) probs[c] = sc[c] * inv;
        }
        __syncthreads();
        #pragma unroll
        for (int i = 0; i < 3; ++i) {
            const int d = t + 256 * i;
            float a = 0.f;
            #pragma unroll
            for (int c = 0; c < 8; ++c)
                a = fmaf(probs[c], meta[c * DIM + d], a);
            att[(which * NPAIR + p) * DIM + d] = a;
        }
        __syncthreads();
    }
}

// ---------------- kernel 2: materialize outputs (pure write bandwidth) ----------------
// grid-stride over 8-float (32B) output chunks; mask folded into the tail range.
// OUTPUT IS FLOAT32.
__global__ __launch_bounds__(256) void k_build(
    const float* __restrict__ prefix,   // (133,1,768) f32
    const float* __restrict__ suffix,   // (133,31,768) f32
    const int* __restrict__ tok_mask,   // (133,40) int32
    const float* __restrict__ sctx,     // (8,768) f32
    const float* __restrict__ octx,     // (8,768) f32
    const float* __restrict__ att,      // (2,32,768) f32
    float* __restrict__ out)
{
    const u32 stride = gridDim.x * 256u;
    for (u32 g = blockIdx.x * 256u + threadIdx.x; g < TOTAL_WORK; g += stride) {
        if (g < TOTAL_MAT) {
            const u32 which = (g >= MAT_VECS) ? 1u : 0u;
            const u32 r = g - which * MAT_VECS;
            const u32 row = r / 96u;            // 96 chunks of 8 per 768-row
            const u32 d0 = (r - row * 96u) * 8u;
            const u32 pair = row / 3680u;       // 92*40
            const u32 rem = row - pair * 3680u;
            const u32 cls = rem / 40u;
            const u32 tok = rem - cls * 40u;
            float* dst = out + (size_t)which * MAT_ELEMS + (size_t)row * DIM + d0;
            float4 o0, o1;
            if (tok == 0u) {
                const float* sp = prefix + (cls + 1u) * DIM + d0;
                o0 = *(const float4*)sp;
                o1 = *(const float4*)(sp + 4);
            } else if (tok < 9u) {
                const float* cp = (which ? octx : sctx) + (tok - 1u) * DIM + d0;
                const float* ap = att + ((which * NPAIR + pair) * DIM + d0);
                const float4 c0 = *(const float4*)cp;
                const float4 c1 = *(const float4*)(cp + 4);
                const float4 a0 = *(const float4*)ap;
                const float4 a1 = *(const float4*)(ap + 4);
                o0.x = c0.x + a0.x; o0.y = c0.y + a0.y; o0.z = c0.z + a0.z; o0.w = c0.w + a0.w;
                o1.x = c1.x + a1.x; o1.y = c1.y + a1.y; o1.z = c1.z + a1.z; o1.w = c1.w + a1.w;
            } else {
                const float* sp = suffix + ((cls + 1u) * 31u + (tok - 9u)) * DIM + d0;
                o0 = *(const float4*)sp;
                o1 = *(const float4*)(sp + 4);
            }
            *(float4*)dst = o0;
            *(float4*)(dst + 4) = o1;
        } else {
            const u32 m = (g - TOTAL_MAT) * 8u;  // mask element base
            float v[8];
            #pragma unroll
            for (int j = 0; j < 8; ++j) {
                const u32 i = m + (u32)j;
                const u32 rw = i / 40u;
                const u32 tk = i - rw * 40u;
                const u32 cls = rw % 92u;
                v[j] = (float)tok_mask[(cls + 1u) * 40u + tk];
            }
            float* dst = out + MASK_BASE + m;
            *(float4*)dst = make_float4(v[0], v[1], v[2], v[3]);
            *(float4*)(dst + 4) = make_float4(v[4], v[5], v[6], v[7]);
        }
    }
}

extern "C" void kernel_launch(void* const* d_in, const int* in_sizes, int n_in,
                              void* d_out, int out_size, void* d_ws, size_t ws_size,
                              hipStream_t stream) {
    const int* so_ids     = (const int*)d_in[0];
    const float* enti     = (const float*)d_in[1];
    const float* prefix   = (const float*)d_in[2];
    const float* suffix   = (const float*)d_in[3];
    const int* tok_mask   = (const int*)d_in[4];
    const float* meta     = (const float*)d_in[5];
    const float* sctx     = (const float*)d_in[6];
    const float* octx     = (const float*)d_in[7];
    const float* W1       = (const float*)d_in[8];
    const float* b1       = (const float*)d_in[9];
    const float* W2       = (const float*)d_in[10];
    float* att = (float*)d_ws;  // (2,32,768) f32 = 196,608 bytes

    k_mlp_att<<<dim3(32), dim3(256), 0, stream>>>(so_ids, enti, meta, W1, b1, W2, att);
    k_build<<<dim3(2048), dim3(256), 0, stream>>>(prefix, suffix, tok_mask, sctx, octx, att,
                                                  (float*)d_out);
}

// Round 6
// 176.079 us; speedup vs baseline: 1.4704x; 1.4704x over previous
//
#include <hip/hip_runtime.h>
#include <hip/hip_bf16.h>

typedef unsigned int u32;
typedef __attribute__((ext_vector_type(4))) float f32x4;

#define NPAIR 32
#define NCLS  92
#define NCTX  8
#define MAXL  40
#define DIM   768
#define LSUF  31

#define MAT_ELEMS 90439680u      // 32*92*40*768  (f32 elements)
#define MASK_BASE 180879360u     // 2*MAT_ELEMS (f32 element offset)
#define NBLK_MAT  7360u          // 2*92*40
#define MASK_F4   29440u         // 117760/4
#define NBLK_MASK 154u           // ceil(29440/192)

// ---------------- kernel 1: gather + MLP + 8-way attention ----------------
// one block per pair, 512 threads, k-split matmuls
__global__ __launch_bounds__(512) void k_mlp_att(
    const int* __restrict__ so_ids,     // (32,2) int32 (int64 layout auto-detected)
    const float* __restrict__ enti,     // (36,256) f32
    const float* __restrict__ meta,     // (8,768) f32
    const float* __restrict__ W1,       // (512,256) f32
    const float* __restrict__ b1,       // (256) f32
    const float* __restrict__ W2,       // (256,1536) f32
    float* __restrict__ att)            // out: (2,32,768) f32 in d_ws
{
    const int p = blockIdx.x;
    const int t = threadIdx.x;
    __shared__ float so_vec[512];
    __shared__ float w1part[2][256];
    __shared__ float h[256];
    __shared__ float w2part[2][1536];
    __shared__ float so_e[1536];
    __shared__ float red[8][512];
    __shared__ float probs[8];
    __shared__ int ids[2];

    if (t == 0) {
        bool is64 = true;
        for (int i = 1; i < 64; i += 2) is64 = is64 && (so_ids[i] == 0);
        if (is64) { ids[0] = so_ids[4 * p];     ids[1] = so_ids[4 * p + 2]; }
        else      { ids[0] = so_ids[2 * p];     ids[1] = so_ids[2 * p + 1]; }
    }
    __syncthreads();
    const int s_id = ids[0];
    const int o_id = ids[1];
    so_vec[t] = (t < 256) ? enti[s_id * 256 + t] : enti[o_id * 256 + (t - 256)];
    __syncthreads();

    // W1: thread (j = t&255, half = t>>8) does 256-long partial dot
    {
        const int j = t & 255, half = t >> 8;
        const float* w = W1 + (half * 256) * 256 + j;
        const float* sv = so_vec + half * 256;
        float acc = 0.f;
        #pragma unroll 8
        for (int kk = 0; kk < 256; ++kk)
            acc = fmaf(sv[kk], w[(size_t)kk * 256], acc);
        w1part[half][j] = acc;
    }
    __syncthreads();
    if (t < 256) h[t] = fmaxf(w1part[0][t] + w1part[1][t] + b1[t], 0.f);
    __syncthreads();

    // W2: thread (c = t&255, khalf = t>>8), 6 columns x 128-long partials
    {
        const int c = t & 255, khalf = t >> 8;
        float a6[6] = {0.f, 0.f, 0.f, 0.f, 0.f, 0.f};
        const float* w = W2 + (khalf * 128) * 1536 + c;
        const float* hh = h + khalf * 128;
        #pragma unroll 4
        for (int kk = 0; kk < 128; ++kk) {
            const float hk = hh[kk];
            #pragma unroll
            for (int r = 0; r < 6; ++r)
                a6[r] = fmaf(hk, w[(size_t)kk * 1536 + r * 256], a6[r]);
        }
        #pragma unroll
        for (int r = 0; r < 6; ++r) w2part[khalf][r * 256 + c] = a6[r];
    }
    __syncthreads();
    for (int c = t; c < 1536; c += 512) so_e[c] = w2part[0][c] + w2part[1][c];
    __syncthreads();

    const float scale = 0.036084391824351615f;  // 1/sqrt(768)
    for (int which = 0; which < 2; ++which) {
        const float* q = &so_e[which * DIM];
        #pragma unroll
        for (int c = 0; c < 8; ++c) {
            float pp = 0.f;
            for (int d = t; d < DIM; d += 512)
                pp = fmaf(q[d], meta[c * DIM + d], pp);
            red[c][t] = pp;
        }
        __syncthreads();
        for (int s = 256; s > 0; s >>= 1) {
            if (t < s) {
                #pragma unroll
                for (int c = 0; c < 8; ++c)
                    red[c][t] += red[c][t + s];
            }
            __syncthreads();
        }
        if (t == 0) {
            float sc[8], m = -1e30f;
            #pragma unroll
            for (int c = 0; c < 8; ++c) { sc[c] = red[c][0] * scale; m = fmaxf(m, sc[c]); }
            float sum = 0.f;
            #pragma unroll
            for (int c = 0; c < 8; ++c) { sc[c] = expf(sc[c] - m); sum += sc[c]; }
            const float inv = 1.f / sum;
            #pragma unroll
            for (int c = 0; c < 8; ++c) probs[c] = sc[c] * inv;
        }
        __syncthreads();
        for (int d = t; d < DIM; d += 512) {
            float a = 0.f;
            #pragma unroll
            for (int c = 0; c < 8; ++c)
                a = fmaf(probs[c], meta[c * DIM + d], a);
            att[(which * NPAIR + p) * DIM + d] = a;
        }
        __syncthreads();
    }
}

// ---------------- kernel 2: broadcast materializer ----------------
// one block per (which, cls, tok) source row; 192 threads; read source once,
// store to all 32 pair destinations with lane-contiguous full-line stores.
__global__ __launch_bounds__(192) void k_build(
    const float* __restrict__ prefix,   // (133,1,768) f32
    const float* __restrict__ suffix,   // (133,31,768) f32
    const int* __restrict__ tok_mask,   // (133,40) int32
    const float* __restrict__ sctx,     // (8,768) f32
    const float* __restrict__ octx,     // (8,768) f32
    const float* __restrict__ att,      // (2,32,768) f32
    float* __restrict__ out)
{
    const u32 bid = blockIdx.x;
    const u32 t = threadIdx.x;

    if (bid < NBLK_MAT) {
        const u32 which = bid / 3680u;          // 92*40
        const u32 rem = bid - which * 3680u;
        const u32 cls = rem / 40u;
        const u32 tok = rem - cls * 40u;
        const u32 d = t * 4u;

        f32x4 src;
        bool is_ctx = false;
        if (tok == 0u) {
            src = *(const f32x4*)(prefix + (cls + 1u) * DIM + d);
        } else if (tok < 9u) {
            const float* cp = (which ? octx : sctx) + (tok - 1u) * DIM + d;
            src = *(const f32x4*)cp;
            is_ctx = true;
        } else {
            src = *(const f32x4*)(suffix + ((cls + 1u) * LSUF + (tok - 9u)) * DIM + d);
        }

        float* base = out + (size_t)which * MAT_ELEMS + (size_t)(cls * MAXL + tok) * DIM + d;
        const float* ab = att + (size_t)which * NPAIR * DIM + d;
        if (is_ctx) {
            #pragma unroll 4
            for (u32 p = 0; p < NPAIR; ++p) {
                const f32x4 a = *(const f32x4*)(ab + (size_t)p * DIM);
                __builtin_nontemporal_store(src + a,
                    (f32x4*)(base + (size_t)p * (NCLS * MAXL * DIM)));
            }
        } else {
            #pragma unroll 4
            for (u32 p = 0; p < NPAIR; ++p) {
                __builtin_nontemporal_store(src,
                    (f32x4*)(base + (size_t)p * (NCLS * MAXL * DIM)));
            }
        }
    } else {
        // mask tail: out[MASK_BASE + ...] = float(tok_mask[(rw%92)+1][tk])
        const u32 idx4 = (bid - NBLK_MAT) * 192u + t;
        if (idx4 < MASK_F4) {
            const u32 m = idx4 * 4u;
            f32x4 v;
            #pragma unroll
            for (int j = 0; j < 4; ++j) {
                const u32 i = m + (u32)j;
                const u32 rw = i / 40u;
                const u32 tk = i - rw * 40u;
                const u32 cls = rw % 92u;
                v[j] = (float)tok_mask[(cls + 1u) * 40u + tk];
            }
            __builtin_nontemporal_store(v, (f32x4*)(out + MASK_BASE + m));
        }
    }
}

extern "C" void kernel_launch(void* const* d_in, const int* in_sizes, int n_in,
                              void* d_out, int out_size, void* d_ws, size_t ws_size,
                              hipStream_t stream) {
    const int* so_ids     = (const int*)d_in[0];
    const float* enti     = (const float*)d_in[1];
    const float* prefix   = (const float*)d_in[2];
    const float* suffix   = (const float*)d_in[3];
    const int* tok_mask   = (const int*)d_in[4];
    const float* meta     = (const float*)d_in[5];
    const float* sctx     = (const float*)d_in[6];
    const float* octx     = (const float*)d_in[7];
    const float* W1       = (const float*)d_in[8];
    const float* b1       = (const float*)d_in[9];
    const float* W2       = (const float*)d_in[10];
    float* att = (float*)d_ws;  // (2,32,768) f32 = 196,608 bytes

    k_mlp_att<<<dim3(NPAIR), dim3(512), 0, stream>>>(so_ids, enti, meta, W1, b1, W2, att);
    k_build<<<dim3(NBLK_MAT + NBLK_MASK), dim3(192), 0, stream>>>(
        prefix, suffix, tok_mask, sctx, octx, att, (float*)d_out);
}

// Round 7
// 166.631 us; speedup vs baseline: 1.5538x; 1.0567x over previous
//
#include <hip/hip_runtime.h>
#include <hip/hip_bf16.h>

typedef unsigned int u32;
typedef __attribute__((ext_vector_type(4))) float f32x4;

#define NPAIR 32
#define NCLS  92
#define NCTX  8
#define MAXL  40
#define DIM   768
#define LSUF  31

#define MAT_ELEMS 90439680u      // 32*92*40*768  (f32 elements)
#define MASK_BASE 180879360u     // 2*MAT_ELEMS (f32 element offset)
#define NBLK_MAT  7360u          // 2*92*40
#define MASK_F4   29440u         // 117760/4
#define NBLK_MASK 154u           // ceil(29440/192)

// d_ws layout (f32 offsets): att[0 .. 49152), h[49152 .. 57344), so_e[57344 .. 106496)
#define WS_ATT  0u
#define WS_H    49152u
#define WS_SOE  57344u

// ---------------- kernel A: h = relu(so @ W1 + b1) ----------------
// one block per pair, 512 threads (k-split by 2)
__global__ __launch_bounds__(512) void k_h(
    const int* __restrict__ so_ids,     // (32,2) int32 (int64 layout auto-detected)
    const float* __restrict__ enti,     // (36,256) f32
    const float* __restrict__ W1,       // (512,256) f32
    const float* __restrict__ b1,       // (256) f32
    float* __restrict__ ws)
{
    const int p = blockIdx.x;
    const int t = threadIdx.x;
    __shared__ float so_vec[512];
    __shared__ float w1part[2][256];
    __shared__ int ids[2];

    if (t == 0) {
        bool is64 = true;
        for (int i = 1; i < 64; i += 2) is64 = is64 && (so_ids[i] == 0);
        if (is64) { ids[0] = so_ids[4 * p];     ids[1] = so_ids[4 * p + 2]; }
        else      { ids[0] = so_ids[2 * p];     ids[1] = so_ids[2 * p + 1]; }
    }
    __syncthreads();
    so_vec[t] = (t < 256) ? enti[ids[0] * 256 + t] : enti[ids[1] * 256 + (t - 256)];
    __syncthreads();

    const int j = t & 255, half = t >> 8;
    const float* w = W1 + (half * 256) * 256 + j;
    const float* sv = so_vec + half * 256;
    float acc = 0.f;
    #pragma unroll 8
    for (int kk = 0; kk < 256; ++kk)
        acc = fmaf(sv[kk], w[(size_t)kk * 256], acc);
    w1part[half][j] = acc;
    __syncthreads();
    if (t < 256)
        ws[WS_H + p * 256 + t] = fmaxf(w1part[0][t] + w1part[1][t] + b1[t], 0.f);
}

// ---------------- kernel B: so_e = h @ W2 ----------------
// grid 192 = (pair 32) x (col-chunk 6), 256 threads; W2 slice read per block
__global__ __launch_bounds__(256) void k_soe(
    const float* __restrict__ W2,       // (256,1536) f32
    float* __restrict__ ws)
{
    const int p = blockIdx.x / 6;
    const int cc = blockIdx.x % 6;
    const int t = threadIdx.x;
    __shared__ float hl[256];
    hl[t] = ws[WS_H + p * 256 + t];
    __syncthreads();

    const int c = cc * 256 + t;
    const float* w = W2 + c;
    float acc = 0.f;
    #pragma unroll 8
    for (int k = 0; k < 256; ++k)
        acc = fmaf(hl[k], w[(size_t)k * 1536], acc);
    ws[WS_SOE + p * 1536 + c] = acc;
}

// ---------------- kernel C: softmax attention ----------------
// grid 64 = (which 2) x (pair 32), 256 threads
__global__ __launch_bounds__(256) void k_att(
    const float* __restrict__ meta,     // (8,768) f32
    float* __restrict__ ws)
{
    const int which = blockIdx.x >> 5;
    const int p = blockIdx.x & 31;
    const int t = threadIdx.x;
    __shared__ float red[8][256];
    __shared__ float probs[8];

    const float* q = ws + WS_SOE + p * 1536 + which * DIM;
    float qr[3];
    #pragma unroll
    for (int i = 0; i < 3; ++i) qr[i] = q[t + 256 * i];

    #pragma unroll
    for (int c = 0; c < 8; ++c) {
        float pp = 0.f;
        #pragma unroll
        for (int i = 0; i < 3; ++i)
            pp = fmaf(qr[i], meta[c * DIM + t + 256 * i], pp);
        red[c][t] = pp;
    }
    __syncthreads();
    for (int s = 128; s > 0; s >>= 1) {
        if (t < s) {
            #pragma unroll
            for (int c = 0; c < 8; ++c)
                red[c][t] += red[c][t + s];
        }
        __syncthreads();
    }
    if (t == 0) {
        const float scale = 0.036084391824351615f;  // 1/sqrt(768)
        float sc[8], m = -1e30f;
        #pragma unroll
        for (int c = 0; c < 8; ++c) { sc[c] = red[c][0] * scale; m = fmaxf(m, sc[c]); }
        float sum = 0.f;
        #pragma unroll
        for (int c = 0; c < 8; ++c) { sc[c] = expf(sc[c] - m); sum += sc[c]; }
        const float inv = 1.f / sum;
        #pragma unroll
        for (int c = 0; c < 8; ++c) probs[c] = sc[c] * inv;
    }
    __syncthreads();
    #pragma unroll
    for (int i = 0; i < 3; ++i) {
        const int d = t + 256 * i;
        float a = 0.f;
        #pragma unroll
        for (int c = 0; c < 8; ++c)
            a = fmaf(probs[c], meta[c * DIM + d], a);
        ws[WS_ATT + (which * NPAIR + p) * DIM + d] = a;
    }
}

// ---------------- kernel D: broadcast materializer ----------------
// one block per (which, cls, tok) source row; 192 threads; read source once,
// store to all 32 pair destinations with lane-contiguous full-line stores.
__global__ __launch_bounds__(192) void k_build(
    const float* __restrict__ prefix,   // (133,1,768) f32
    const float* __restrict__ suffix,   // (133,31,768) f32
    const int* __restrict__ tok_mask,   // (133,40) int32
    const float* __restrict__ sctx,     // (8,768) f32
    const float* __restrict__ octx,     // (8,768) f32
    const float* __restrict__ att,      // (2,32,768) f32 (in d_ws)
    float* __restrict__ out)
{
    const u32 bid = blockIdx.x;
    const u32 t = threadIdx.x;

    if (bid < NBLK_MAT) {
        const u32 which = bid / 3680u;          // 92*40
        const u32 rem = bid - which * 3680u;
        const u32 cls = rem / 40u;
        const u32 tok = rem - cls * 40u;
        const u32 d = t * 4u;

        f32x4 src;
        bool is_ctx = false;
        if (tok == 0u) {
            src = *(const f32x4*)(prefix + (cls + 1u) * DIM + d);
        } else if (tok < 9u) {
            const float* cp = (which ? octx : sctx) + (tok - 1u) * DIM + d;
            src = *(const f32x4*)cp;
            is_ctx = true;
        } else {
            src = *(const f32x4*)(suffix + ((cls + 1u) * LSUF + (tok - 9u)) * DIM + d);
        }

        float* base = out + (size_t)which * MAT_ELEMS + (size_t)(cls * MAXL + tok) * DIM + d;
        const float* ab = att + (size_t)which * NPAIR * DIM + d;
        if (is_ctx) {
            #pragma unroll 4
            for (u32 p = 0; p < NPAIR; ++p) {
                const f32x4 a = *(const f32x4*)(ab + (size_t)p * DIM);
                __builtin_nontemporal_store(src + a,
                    (f32x4*)(base + (size_t)p * (NCLS * MAXL * DIM)));
            }
        } else {
            #pragma unroll 4
            for (u32 p = 0; p < NPAIR; ++p) {
                __builtin_nontemporal_store(src,
                    (f32x4*)(base + (size_t)p * (NCLS * MAXL * DIM)));
            }
        }
    } else {
        // mask tail: out[MASK_BASE + ...] = float(tok_mask[(rw%92)+1][tk])
        const u32 idx4 = (bid - NBLK_MAT) * 192u + t;
        if (idx4 < MASK_F4) {
            const u32 m = idx4 * 4u;
            f32x4 v;
            #pragma unroll
            for (int j = 0; j < 4; ++j) {
                const u32 i = m + (u32)j;
                const u32 rw = i / 40u;
                const u32 tk = i - rw * 40u;
                const u32 cls = rw % 92u;
                v[j] = (float)tok_mask[(cls + 1u) * 40u + tk];
            }
            __builtin_nontemporal_store(v, (f32x4*)(out + MASK_BASE + m));
        }
    }
}

extern "C" void kernel_launch(void* const* d_in, const int* in_sizes, int n_in,
                              void* d_out, int out_size, void* d_ws, size_t ws_size,
                              hipStream_t stream) {
    const int* so_ids     = (const int*)d_in[0];
    const float* enti     = (const float*)d_in[1];
    const float* prefix   = (const float*)d_in[2];
    const float* suffix   = (const float*)d_in[3];
    const int* tok_mask   = (const int*)d_in[4];
    const float* meta     = (const float*)d_in[5];
    const float* sctx     = (const float*)d_in[6];
    const float* octx     = (const float*)d_in[7];
    const float* W1       = (const float*)d_in[8];
    const float* b1       = (const float*)d_in[9];
    const float* W2       = (const float*)d_in[10];
    float* ws = (float*)d_ws;   // 426 KB used: att | h | so_e

    k_h  <<<dim3(NPAIR), dim3(512), 0, stream>>>(so_ids, enti, W1, b1, ws);
    k_soe<<<dim3(192),   dim3(256), 0, stream>>>(W2, ws);
    k_att<<<dim3(64),    dim3(256), 0, stream>>>(meta, ws);
    k_build<<<dim3(NBLK_MAT + NBLK_MASK), dim3(192), 0, stream>>>(
        prefix, suffix, tok_mask, sctx, octx, ws + WS_ATT, (float*)d_out);
}